// Round 3
// baseline (136.218 us; speedup 1.0000x reference)
//
#include <hip/hip_runtime.h>
#include <math.h>

#define PP 4096   // P = H*W
#define CC 256    // channels
#define NN 2      // batch

typedef __attribute__((ext_vector_type(4))) float f32x4;

__device__ __forceinline__ void gld_lds16(const char* g, char* l) {
    __builtin_amdgcn_global_load_lds(
        (const __attribute__((address_space(1))) unsigned int*)g,
        (__attribute__((address_space(3))) unsigned int*)l, 16, 0, 0);
}

// [journal r11/r12: hipLaunchCooperativeKernel is NOT graph-capture-safe in this
//  harness (silent no-launch -> out=0), and grid.sync does NOT make plain
//  cross-XCD stores visible (L2 dirty-line race -> garbage). Do NOT retry
//  cooperative fusion. Launch-count reduction must use the last-block pattern
//  with agent-scope atomics only.]
// [journal r10: MX-scaled MFMA regressed (+7us) -- GEMM is not MFMA-bound at
//  occupancy 3; keep non-scaled 16x16x32 fp8 + launch_bounds(512,6).]
// [journal r6/r7: NEVER put device-scope __threadfence in a hot epilogue -
//  L2 writeback storm, 10x. Visibility here comes from agent-scope atomics +
//  the vmcnt(0) drain the compiler emits before s_barrier.]

// ---- kernel 1: meanT[c] = mean over (n,p) of T (float4 loads); init stats ----
__global__ __launch_bounds__(256) void mean_kernel(const float* __restrict__ T,
                                                   float* __restrict__ meanT,
                                                   unsigned* __restrict__ mn_enc,
                                                   float* __restrict__ S,
                                                   float* __restrict__ diagw,
                                                   unsigned* __restrict__ cnt) {
    int c = blockIdx.x, tid = threadIdx.x;
    float s = 0.f;
    for (int n = 0; n < NN; n++) {
        const float4* Tc = (const float4*)&T[(size_t)(n * CC + c) * PP];
        for (int g = 0; g < 4; g++) {
            float4 v = Tc[tid + g * 256];
            s += (v.x + v.y) + (v.z + v.w);
        }
    }
    __shared__ float red[256];
    red[tid] = s; __syncthreads();
    for (int st = 128; st > 0; st >>= 1) {
        if (tid < st) red[tid] += red[tid + st];
        __syncthreads();
    }
    if (tid == 0) meanT[c] = red[0] * (1.0f / (NN * PP));
    // init stats: 256 blocks x 32 entries = NN*PP = 8192
    int base = blockIdx.x * 32;
    if (tid < 32) {
        mn_enc[base + tid] = 0xFFFFFFFFu;  // +inf in monotone-uint encoding
        S[base + tid] = 0.f;
        diagw[base + tid] = 0.f;
    }
    if (blockIdx.x == 0 && tid == 0) cnt[0] = 0u;  // last-block counter
}

// ---- kernel 2: center by meanT, L2-normalize over C, write FP8 e4m3 [n][p][c] ----
// float4 loads over contiguous p; tile pad = 36 floats (144 B rows, 16B aligned).
__global__ __launch_bounds__(256) void normalize_kernel(const float* __restrict__ I,
                                                        const float* __restrict__ T,
                                                        const float* __restrict__ meanT,
                                                        char* __restrict__ InT,
                                                        char* __restrict__ TnT) {
    int pc = blockIdx.x * 32;      // 32 positions per block
    int n = blockIdx.y;
    int which = blockIdx.z;        // 0: I -> InT, 1: T -> TnT
    const float* X = which ? T : I;
    char* Y = which ? TnT : InT;

    __shared__ float tile[CC][36];   // [c][p_local], pad 36 (16B-aligned rows)
    __shared__ float red[32][32];    // [c-group][p_local]
    __shared__ float invn[32];

    int tid = threadIdx.x;
    int pl4 = tid & 7, c0 = tid >> 3;   // 32 c-groups x 8 p-quads
    float sq0 = 0.f, sq1 = 0.f, sq2 = 0.f, sq3 = 0.f;
    for (int c = c0; c < CC; c += 32) {
        float m = meanT[c];
        float4 v = *(const float4*)&X[(size_t)(n * CC + c) * PP + pc + pl4 * 4];
        v.x -= m; v.y -= m; v.z -= m; v.w -= m;
        *(float4*)&tile[c][pl4 * 4] = v;
        sq0 += v.x * v.x; sq1 += v.y * v.y; sq2 += v.z * v.z; sq3 += v.w * v.w;
    }
    red[c0][pl4 * 4 + 0] = sq0;
    red[c0][pl4 * 4 + 1] = sq1;
    red[c0][pl4 * 4 + 2] = sq2;
    red[c0][pl4 * 4 + 3] = sq3;
    __syncthreads();
    if (tid < 32) {
        float s = 0.f;
        for (int k = 0; k < 32; k++) s += red[k][tid];
        invn[tid] = 1.0f / sqrtf(s);
    }
    __syncthreads();
    // write fp8: 4 channels per thread (4B store), 4 rows per pass, 8 passes
    for (int pass = 0; pass < 8; pass++) {
        int r = pass * 4 + (tid >> 6);
        int c4 = (tid & 63) * 4;
        float in = invn[r];
        float v0 = tile[c4 + 0][r] * in;
        float v1 = tile[c4 + 1][r] * in;
        float v2 = tile[c4 + 2][r] * in;
        float v3 = tile[c4 + 3][r] * in;
        int w = __builtin_amdgcn_cvt_pk_fp8_f32(v0, v1, 0, false);
        w = __builtin_amdgcn_cvt_pk_fp8_f32(v2, v3, w, true);
        *(unsigned*)&Y[(size_t)(n * PP + pc + r) * CC + c4] = (unsigned)w;
    }
}

// ---- kernel 3: FP8 NT-GEMM sweep 0: column (over q) min of raw=(1-dot)/2 ----
// 128x128 tile, BK=128 (two k-iters), 8 waves (32x64 each via 2x4 16x16x32_fp8
// MFMA, 32 acc regs), launch_bounds(512,6), LDS 34 KB, global_load_lds 16B.
// Swizzle: stored 16B slot s of row r holds global chunk s^((r>>1)&7); read byte
// pos = (c ^ (lm&14))*8.  [byte-identical math to validated round-0, absmax 0.0]
__global__ __launch_bounds__(512, 6) void cx_gemm0(const char* __restrict__ TnT,
                                                   const char* __restrict__ InT,
                                                   unsigned* __restrict__ mn_enc) {
    const int n = blockIdx.z;
    const char* __restrict__ A = TnT + (size_t)n * PP * CC;  // A[q*CC + c]
    const char* __restrict__ B = InT + (size_t)n * PP * CC;  // B[p*CC + c]
    const int q0 = blockIdx.y * 128, p0 = blockIdx.x * 128;

    __shared__ __align__(16) char As[128 * 128];  // 16 KB
    __shared__ __align__(16) char Bs[128 * 128];  // 16 KB
    __shared__ float red[8][64];                  // 2 KB

    const int tid = threadIdx.x;
    const int l = tid & 63, wv = tid >> 6;
    const int lm = l & 15, quad = l >> 4;
    const int wr = (wv & 3) * 32, wc = (wv >> 2) * 64;

    const int srow = tid >> 3;
    const int gk = ((tid & 7) ^ ((srow >> 1) & 7)) * 16;
    const char* Ag = A + (size_t)(q0 + srow) * CC + gk;
    const char* Bg = B + (size_t)(p0 + srow) * CC + gk;
    char* Al = As + tid * 16;
    char* Bl = Bs + tid * 16;

    f32x4 acc[2][4] = {};
    const int rsw = (lm & 14);

#pragma unroll
    for (int it = 0; it < 2; it++) {
        __syncthreads();
        gld_lds16(Ag + it * 128, Al);
        gld_lds16(Ag + 64 * CC + it * 128, Al + 8192);
        gld_lds16(Bg + it * 128, Bl);
        gld_lds16(Bg + 64 * CC + it * 128, Bl + 8192);
        __syncthreads();

#pragma unroll
        for (int ksub = 0; ksub < 4; ksub++) {
            const int c = ksub * 4 + quad;
            long a[2], b[4];
#pragma unroll
            for (int i = 0; i < 2; i++)
                a[i] = *(const long*)&As[(wr + i * 16 + lm) * 128 + (c ^ rsw) * 8];
#pragma unroll
            for (int j = 0; j < 4; j++)
                b[j] = *(const long*)&Bs[(wc + j * 16 + lm) * 128 + (c ^ rsw) * 8];
#pragma unroll
            for (int i = 0; i < 2; i++)
#pragma unroll
                for (int j = 0; j < 4; j++)
                    acc[i][j] = __builtin_amdgcn_mfma_f32_16x16x32_fp8_fp8(a[i], b[j], acc[i][j], 0, 0, 0);
        }
    }

    // C/D layout: col = lm, row = quad*4 + reg (within each 16x16 tile)
#pragma unroll
    for (int j = 0; j < 4; j++) {
        float m = 3.4e38f;
#pragma unroll
        for (int i = 0; i < 2; i++)
#pragma unroll
            for (int e = 0; e < 4; e++)
                m = fminf(m, (1.0f - acc[i][j][e]) * 0.5f);
        m = fminf(m, __shfl_xor(m, 16));
        m = fminf(m, __shfl_xor(m, 32));
        if (quad == 0) red[wv][j * 16 + lm] = m;
    }
    __syncthreads();
    if (tid < 128) {
        int grp = tid >> 6, idx = tid & 63;
        float m = fminf(fminf(red[grp * 4 + 0][idx], red[grp * 4 + 1][idx]),
                        fminf(red[grp * 4 + 2][idx], red[grp * 4 + 3][idx]));
        unsigned u = __float_as_uint(m);
        u = (u & 0x80000000u) ? ~u : (u | 0x80000000u);  // monotone encoding
        atomicMin(&mn_enc[n * PP + p0 + tid], u);
    }
}

// ---- kernel 4: sweep 1 (exp-weight col sums + diag) + last-block finalize ----
// diagw written via agent-scope atomic store (write-through, no dirty-L2 race);
// S via atomicAdd (coherent-point RMW). After the epilogue barrier (compiler
// drains vmcnt(0) first), tid0 acq-rel increments cnt; block seeing old==2047
// finalizes, reading S/diagw with agent-scope relaxed atomic loads.
#define NT_BLOCKS ((PP / 128) * (PP / 128) * NN)  // 2048
__global__ __launch_bounds__(512, 6) void cx_gemm1(const char* __restrict__ TnT,
                                                   const char* __restrict__ InT,
                                                   const unsigned* __restrict__ mn_enc,
                                                   float* __restrict__ S,
                                                   float* __restrict__ diagw,
                                                   unsigned* __restrict__ cnt,
                                                   float* __restrict__ out) {
    const int n = blockIdx.z;
    const char* __restrict__ A = TnT + (size_t)n * PP * CC;
    const char* __restrict__ B = InT + (size_t)n * PP * CC;
    const int q0 = blockIdx.y * 128, p0 = blockIdx.x * 128;

    __shared__ __align__(16) char As[128 * 128];
    __shared__ __align__(16) char Bs[128 * 128];
    __shared__ float red[8][64];
    __shared__ bool isLast;

    const int tid = threadIdx.x;
    const int l = tid & 63, wv = tid >> 6;
    const int lm = l & 15, quad = l >> 4;
    const int wr = (wv & 3) * 32, wc = (wv >> 2) * 64;

    const int srow = tid >> 3;
    const int gk = ((tid & 7) ^ ((srow >> 1) & 7)) * 16;
    const char* Ag = A + (size_t)(q0 + srow) * CC + gk;
    const char* Bg = B + (size_t)(p0 + srow) * CC + gk;
    char* Al = As + tid * 16;
    char* Bl = Bs + tid * 16;

    f32x4 acc[2][4] = {};
    const int rsw = (lm & 14);

#pragma unroll
    for (int it = 0; it < 2; it++) {
        __syncthreads();
        gld_lds16(Ag + it * 128, Al);
        gld_lds16(Ag + 64 * CC + it * 128, Al + 8192);
        gld_lds16(Bg + it * 128, Bl);
        gld_lds16(Bg + 64 * CC + it * 128, Bl + 8192);
        __syncthreads();

#pragma unroll
        for (int ksub = 0; ksub < 4; ksub++) {
            const int c = ksub * 4 + quad;
            long a[2], b[4];
#pragma unroll
            for (int i = 0; i < 2; i++)
                a[i] = *(const long*)&As[(wr + i * 16 + lm) * 128 + (c ^ rsw) * 8];
#pragma unroll
            for (int j = 0; j < 4; j++)
                b[j] = *(const long*)&Bs[(wc + j * 16 + lm) * 128 + (c ^ rsw) * 8];
#pragma unroll
            for (int i = 0; i < 2; i++)
#pragma unroll
                for (int j = 0; j < 4; j++)
                    acc[i][j] = __builtin_amdgcn_mfma_f32_16x16x32_fp8_fp8(a[i], b[j], acc[i][j], 0, 0, 0);
        }
    }

#pragma unroll
    for (int j = 0; j < 4; j++) {
        const int col = p0 + wc + j * 16 + lm;  // global p
        unsigned e = mn_enc[n * PP + col];
        unsigned u = (e & 0x80000000u) ? (e & 0x7fffffffu) : ~e;  // decode
        float mnv = __uint_as_float(u);
        // w = exp(10 - 10*raw/(mn+eps)) = exp2(14.4269504 - raw*inv2)
        float inv2 = 14.4269504f / (mnv + 1e-5f);
        float s = 0.f;
#pragma unroll
        for (int i = 0; i < 2; i++)
#pragma unroll
            for (int e2 = 0; e2 < 4; e2++) {
                float raw = (1.0f - acc[i][j][e2]) * 0.5f;
                float w = exp2f(fmaf(raw, -inv2, 14.4269504f));
                s += w;
                int q = q0 + wr + i * 16 + quad * 4 + e2;  // global q
                if (q == col)                              // unique writer
                    __hip_atomic_store(&diagw[n * PP + q], w, __ATOMIC_RELAXED,
                                       __HIP_MEMORY_SCOPE_AGENT);
            }
        s += __shfl_xor(s, 16);
        s += __shfl_xor(s, 32);
        if (quad == 0) red[wv][j * 16 + lm] = s;
    }
    __syncthreads();
    if (tid < 128) {
        int grp = tid >> 6, idx = tid & 63;
        float s = red[grp * 4 + 0][idx] + red[grp * 4 + 1][idx] +
                  red[grp * 4 + 2][idx] + red[grp * 4 + 3][idx];
        atomicAdd(&S[n * PP + p0 + tid], s);
    }
    // barrier drains vmcnt(0): this block's atomics/stores globally performed
    __syncthreads();
    if (tid == 0) {
        unsigned old = __hip_atomic_fetch_add(cnt, 1u, __ATOMIC_ACQ_REL,
                                              __HIP_MEMORY_SCOPE_AGENT);
        isLast = (old == NT_BLOCKS - 1);
    }
    __syncthreads();
    if (!isLast) return;

    // ---- finalize (runs in exactly one block, after all others incremented) ----
    int fn = tid >> 8, tt = tid & 255;  // 256 threads per sample
    float s = 0.f;
#pragma unroll
    for (int g = 0; g < 16; g++) {
        int idx = fn * PP + tt + g * 256;
        float d = __hip_atomic_load(&diagw[idx], __ATOMIC_RELAXED,
                                    __HIP_MEMORY_SCOPE_AGENT);
        float v = __hip_atomic_load(&S[idx], __ATOMIC_RELAXED,
                                    __HIP_MEMORY_SCOPE_AGENT);
        s += d / v;
    }
    float* r = &red[0][0];
    r[tid] = s; __syncthreads();
    for (int st = 128; st > 0; st >>= 1) {
        if (tt < st) r[fn * 256 + tt] += r[fn * 256 + tt + st];
        __syncthreads();
    }
    if (tid == 0) {
        float m0 = 0.5f + 0.5f * (r[0] / (float)PP);
        float m1 = 0.5f + 0.5f * (r[256] / (float)PP);
        out[0] = 0.5f * (-logf(m0) - logf(m1));
    }
}

extern "C" void kernel_launch(void* const* d_in, const int* in_sizes, int n_in,
                              void* d_out, int out_size, void* d_ws, size_t ws_size,
                              hipStream_t stream) {
    const float* I = (const float*)d_in[0];
    const float* T = (const float*)d_in[1];
    float* out = (float*)d_out;

    char* ws = (char*)d_ws;
    const size_t SZ_F8 = (size_t)NN * PP * CC;  // 2 MB each (fp8)
    char* InT = ws;
    char* TnT = ws + SZ_F8;
    float* meanT = (float*)(ws + 2 * SZ_F8);               // 1 KB
    unsigned* mn = (unsigned*)(ws + 2 * SZ_F8 + 32768);    // 32 KB
    float* S = (float*)(ws + 2 * SZ_F8 + 2 * 32768);       // 32 KB
    float* diagw = (float*)(ws + 2 * SZ_F8 + 3 * 32768);   // 32 KB
    unsigned* cnt = (unsigned*)(ws + 2 * SZ_F8 + 4 * 32768);

    mean_kernel<<<CC, 256, 0, stream>>>(T, meanT, mn, S, diagw, cnt);
    normalize_kernel<<<dim3(PP / 32, NN, 2), 256, 0, stream>>>(I, T, meanT, InT, TnT);
    cx_gemm0<<<dim3(PP / 128, PP / 128, NN), 512, 0, stream>>>(TnT, InT, mn);
    cx_gemm1<<<dim3(PP / 128, PP / 128, NN), 512, 0, stream>>>(TnT, InT, mn, S,
                                                               diagw, cnt, out);
}

// Round 5
// 121.922 us; speedup vs baseline: 1.1173x; 1.1173x over previous
//
#include <hip/hip_runtime.h>
#include <math.h>

#define PP 4096   // P = H*W
#define CC 256    // channels
#define NN 2      // batch
#define QS 256    // q rows per step in strip kernel
#define NSTEP (PP / QS)  // 16

typedef __attribute__((ext_vector_type(4))) float f32x4;

__device__ __forceinline__ void gld_lds16(const char* g, char* l) {
    __builtin_amdgcn_global_load_lds(
        (const __attribute__((address_space(1))) unsigned int*)g,
        (__attribute__((address_space(3))) unsigned int*)l, 16, 0, 0);
}

// [journal r14: round-4 (raw s_barrier + hand-counted vmcnt pipeline) died with
//  "container failed twice" -- possible wave-hang from manual waitcnt counting.
//  NEVER hand-count vmcnt in a kernel that must not hang; use the 2-phase
//  __syncthreads recipe (issue-before-compute, barrier drains) -- ~92% of the
//  deep pipeline per guide T3, zero hang surface.]
// [journal r13: per-block agent-scope ACQ_REL fences in 2048-block kernels cost
//  +40us (fence storm). Strip kernel: block-local stats, ONE atomicAdd each.]
// [journal r11/r12: hipLaunchCooperativeKernel NOT graph-capture-safe here;
//  grid.sync does NOT flush cross-XCD L2. Do not retry cooperative fusion.]
// [journal r10: MX-scaled MFMA regressed -- GEMM is not MFMA-bound. Keep
//  non-scaled 16x16x32 fp8.]

// ---- kernel 1: meanT[c] = mean over (n,p) of T (float4 loads); init loss ----
__global__ __launch_bounds__(256) void mean_kernel(const float* __restrict__ T,
                                                   float* __restrict__ meanT,
                                                   float* __restrict__ loss_acc) {
    int c = blockIdx.x, tid = threadIdx.x;
    float s = 0.f;
    for (int n = 0; n < NN; n++) {
        const float4* Tc = (const float4*)&T[(size_t)(n * CC + c) * PP];
        for (int g = 0; g < 4; g++) {
            float4 v = Tc[tid + g * 256];
            s += (v.x + v.y) + (v.z + v.w);
        }
    }
    __shared__ float red[256];
    red[tid] = s; __syncthreads();
    for (int st = 128; st > 0; st >>= 1) {
        if (tid < st) red[tid] += red[tid + st];
        __syncthreads();
    }
    if (tid == 0) meanT[c] = red[0] * (1.0f / (NN * PP));
    if (blockIdx.x == 0 && tid < NN) loss_acc[tid] = 0.f;
}

// ---- kernel 2: center by meanT, L2-normalize over C, write FP8 e4m3 [n][p][c] ----
__global__ __launch_bounds__(256) void normalize_kernel(const float* __restrict__ I,
                                                        const float* __restrict__ T,
                                                        const float* __restrict__ meanT,
                                                        char* __restrict__ InT,
                                                        char* __restrict__ TnT) {
    int pc = blockIdx.x * 32;      // 32 positions per block
    int n = blockIdx.y;
    int which = blockIdx.z;        // 0: I -> InT, 1: T -> TnT
    const float* X = which ? T : I;
    char* Y = which ? TnT : InT;

    __shared__ float tile[CC][36];   // [c][p_local], pad 36 (16B-aligned rows)
    __shared__ float red[32][32];    // [c-group][p_local]
    __shared__ float invn[32];

    int tid = threadIdx.x;
    int pl4 = tid & 7, c0 = tid >> 3;   // 32 c-groups x 8 p-quads
    float sq0 = 0.f, sq1 = 0.f, sq2 = 0.f, sq3 = 0.f;
    for (int c = c0; c < CC; c += 32) {
        float m = meanT[c];
        float4 v = *(const float4*)&X[(size_t)(n * CC + c) * PP + pc + pl4 * 4];
        v.x -= m; v.y -= m; v.z -= m; v.w -= m;
        *(float4*)&tile[c][pl4 * 4] = v;
        sq0 += v.x * v.x; sq1 += v.y * v.y; sq2 += v.z * v.z; sq3 += v.w * v.w;
    }
    red[c0][pl4 * 4 + 0] = sq0;
    red[c0][pl4 * 4 + 1] = sq1;
    red[c0][pl4 * 4 + 2] = sq2;
    red[c0][pl4 * 4 + 3] = sq3;
    __syncthreads();
    if (tid < 32) {
        float s = 0.f;
        for (int k = 0; k < 32; k++) s += red[k][tid];
        invn[tid] = 1.0f / sqrtf(s);
    }
    __syncthreads();
    for (int pass = 0; pass < 8; pass++) {
        int r = pass * 4 + (tid >> 6);
        int c4 = (tid & 63) * 4;
        float in = invn[r];
        float v0 = tile[c4 + 0][r] * in;
        float v1 = tile[c4 + 1][r] * in;
        float v2 = tile[c4 + 2][r] * in;
        float v3 = tile[c4 + 3][r] * in;
        int w = __builtin_amdgcn_cvt_pk_fp8_f32(v0, v1, 0, false);
        w = __builtin_amdgcn_cvt_pk_fp8_f32(v2, v3, w, true);
        *(unsigned*)&Y[(size_t)(n * PP + pc + r) * CC + c4] = (unsigned)w;
    }
}

// ---- kernel 3: strip kernel -- each block owns 32 p-columns x all 4096 q ----
// Pass 0: col-min of raw=(1-dot)/2 block-locally. Pass 1: recompute dots
// (flash-style), w=exp2(14.427-raw*inv2), col-sums S + diag w, then ONE
// atomicAdd(loss_acc[n], sum_strip(diag/S)) per block. No inter-block state.
// B-strip (32 rows x 256B) hoisted to 32 VGPR of b-frags after one LDS stage.
// A streams: 16 steps x 64KB double-buffered LDS via gld_lds16, 2-phase
// schedule: issue next-step loads BEFORE compute, one __syncthreads per step
// (drains vmcnt+lgkm, orders buffer reuse). Chunk-XOR swizzle: LDS slot s of
// row r holds global 16B chunk s^(r&15); read addr for 8B granule g8 =
// r*256 + ((g8>>1)^(r&15))*16 + (g8&1)*8 -> 2-way bank alias only (free).
__global__ __launch_bounds__(512) void cx_strip(const char* __restrict__ TnT,
                                                const char* __restrict__ InT,
                                                float* __restrict__ loss_acc) {
    const int strip = blockIdx.x;       // 0..127
    const int n = blockIdx.y;
    const int p0 = strip * 32;
    const char* __restrict__ Ab = TnT + (size_t)n * PP * CC;            // q rows
    const char* __restrict__ Bb = InT + (size_t)n * PP * CC + (size_t)p0 * CC;

    __shared__ __align__(16) char As[2][QS * 256];  // 2 x 64 KB
    __shared__ __align__(16) char Bs[32 * 256];     // 8 KB
    __shared__ float redw[8][32];
    __shared__ float inv2s[32];
    __shared__ float dwl[32];

    const int tid = threadIdx.x;
    const int l = tid & 63, wv = tid >> 6;
    const int lm = l & 15, quad = l >> 4;

    // staging map: thread t covers (row = g*32 + (t>>4), chunk slot t&15);
    // global src chunk = (t&15) ^ (row&15)  [row&15 == (t>>4)&15]
    const int srl = tid >> 4;                                  // 0..31
    const int sch = ((tid & 15) ^ (srl & 15)) * 16;
    const char* Asrc = Ab + srl * 256 + sch;
    char* Alds = (char*)As + tid * 16;

    // B staged once (1 issue); drained by the first per-pass __syncthreads
    gld_lds16(Bb + srl * 256 + sch, (char*)Bs + tid * 16);

    long bf[2][8];          // b-frags, hoisted after pass-0 prologue barrier
    float cm[2] = {3.4e38f, 3.4e38f};
    float inv2[2] = {0.f, 0.f};
    float ss[2] = {0.f, 0.f};
    const int qd = p0 >> 8;        // diag step (qd*256 + wd*32 == p0)
    const int wd = (p0 >> 5) & 7;  // diag wave

#pragma unroll 1
    for (int pass = 0; pass < 2; pass++) {
        // stage A step 0 into buf0 (pass 0: initial; pass 1: restage --
        // safe: all pass-0 reads of buf0 retired before its last overwrite
        // barrier, and every step ends in a full-drain __syncthreads)
#pragma unroll
        for (int g = 0; g < 8; g++)
            gld_lds16(Asrc + g * 8192, Alds + g * 8192);
        __syncthreads();   // drains vmcnt(0): buf0 (+B on pass 0) visible

        if (pass == 0) {
            // hoist b-frags: bf[ct][ks], 8B each (32 VGPR total)
#pragma unroll
            for (int ct = 0; ct < 2; ct++)
#pragma unroll
                for (int ks = 0; ks < 8; ks++) {
                    int g8 = ks * 4 + quad;
                    int row = ct * 16 + lm;
                    bf[ct][ks] = *(const long*)&Bs[row * 256 +
                                  (((g8 >> 1) ^ (row & 15)) * 16) + (g8 & 1) * 8];
                }
        }

#pragma unroll 1
        for (int qs = 0; qs < NSTEP; qs++) {
            // issue next-step staging BEFORE compute (overlaps with MFMA;
            // drained by the bottom __syncthreads)
            if (qs < NSTEP - 1) {
                const char* s = Asrc + (size_t)(qs + 1) * 65536;
                char* d = Alds + ((qs + 1) & 1) * 65536;
#pragma unroll
                for (int g = 0; g < 8; g++)
                    gld_lds16(s + g * 8192, d + g * 8192);
            }

            const char* Ac = (const char*)As + (qs & 1) * 65536;
            f32x4 acc[2][2] = {};
#pragma unroll
            for (int ks = 0; ks < 8; ks++) {
                const int off = (((ks * 2 + (quad >> 1)) ^ lm) * 16) + (quad & 1) * 8;
                long a[2];
#pragma unroll
                for (int i = 0; i < 2; i++)
                    a[i] = *(const long*)&Ac[(wv * 32 + i * 16 + lm) * 256 + off];
#pragma unroll
                for (int i = 0; i < 2; i++)
#pragma unroll
                    for (int ct = 0; ct < 2; ct++)
                        acc[i][ct] = __builtin_amdgcn_mfma_f32_16x16x32_fp8_fp8(
                            a[i], bf[ct][ks], acc[i][ct], 0, 0, 0);
            }
            if (pass == 0) {
#pragma unroll
                for (int ct = 0; ct < 2; ct++)
#pragma unroll
                    for (int i = 0; i < 2; i++)
#pragma unroll
                        for (int e = 0; e < 4; e++)
                            cm[ct] = fminf(cm[ct], (1.0f - acc[i][ct][e]) * 0.5f);
            } else {
                const bool dstep = (qs == qd) && (wv == wd);
#pragma unroll
                for (int ct = 0; ct < 2; ct++) {
                    float s2 = 0.f;
#pragma unroll
                    for (int i = 0; i < 2; i++)
#pragma unroll
                        for (int e = 0; e < 4; e++) {
                            float raw = (1.0f - acc[i][ct][e]) * 0.5f;
                            float w = exp2f(fmaf(raw, -inv2[ct], 14.4269504f));
                            s2 += w;
                            // diag: q = p0+i*16+quad*4+e matches p = p0+ct*16+lm
                            if (dstep && (i * 16 + quad * 4 + e == ct * 16 + lm))
                                dwl[ct * 16 + lm] = w;
                        }
                    ss[ct] += s2;
                }
            }
            // one barrier per step: drains this step's staging (next buf ready)
            // AND ensures all waves finished reading buf[qs&1] before it is
            // overwritten at qs+1's issue.
            __syncthreads();
        }

        if (pass == 0) {  // reduce col-mins -> inv2 per col
#pragma unroll
            for (int ct = 0; ct < 2; ct++) {
                cm[ct] = fminf(cm[ct], __shfl_xor(cm[ct], 16));
                cm[ct] = fminf(cm[ct], __shfl_xor(cm[ct], 32));
                if (quad == 0) redw[wv][ct * 16 + lm] = cm[ct];
            }
            __syncthreads();
            if (tid < 32) {
                float m = redw[0][tid];
#pragma unroll
                for (int w2 = 1; w2 < 8; w2++) m = fminf(m, redw[w2][tid]);
                inv2s[tid] = 14.4269504f / (m + 1e-5f);
            }
            __syncthreads();
            inv2[0] = inv2s[lm];
            inv2[1] = inv2s[16 + lm];
        }
    }

    // final: S per col, then partial loss = sum_c dwl[c]/S[c], one atomicAdd
#pragma unroll
    for (int ct = 0; ct < 2; ct++) {
        ss[ct] += __shfl_xor(ss[ct], 16);
        ss[ct] += __shfl_xor(ss[ct], 32);
        if (quad == 0) redw[wv][ct * 16 + lm] = ss[ct];
    }
    __syncthreads();
    if (tid < 32) {
        float s = 0.f;
#pragma unroll
        for (int w2 = 0; w2 < 8; w2++) s += redw[w2][tid];
        float part = dwl[tid] / s;
        part += __shfl_xor(part, 1);
        part += __shfl_xor(part, 2);
        part += __shfl_xor(part, 4);
        part += __shfl_xor(part, 8);
        part += __shfl_xor(part, 16);
        if (tid == 0) atomicAdd(&loss_acc[n], part);
    }
}

// ---- kernel 4: loss = mean_n -log(0.5 + 0.5 * acc_n/P) ----
__global__ void finalize_kernel(const float* __restrict__ loss_acc,
                                float* __restrict__ out) {
    float m0 = 0.5f + 0.5f * (loss_acc[0] / (float)PP);
    float m1 = 0.5f + 0.5f * (loss_acc[1] / (float)PP);
    out[0] = 0.5f * (-logf(m0) - logf(m1));
}

extern "C" void kernel_launch(void* const* d_in, const int* in_sizes, int n_in,
                              void* d_out, int out_size, void* d_ws, size_t ws_size,
                              hipStream_t stream) {
    const float* I = (const float*)d_in[0];
    const float* T = (const float*)d_in[1];
    float* out = (float*)d_out;

    char* ws = (char*)d_ws;
    const size_t SZ_F8 = (size_t)NN * PP * CC;  // 2 MB each (fp8)
    char* InT = ws;
    char* TnT = ws + SZ_F8;
    float* meanT = (float*)(ws + 2 * SZ_F8);               // 1 KB
    float* loss_acc = (float*)(ws + 2 * SZ_F8 + 32768);    // 8 B

    mean_kernel<<<CC, 256, 0, stream>>>(T, meanT, loss_acc);
    normalize_kernel<<<dim3(PP / 32, NN, 2), 256, 0, stream>>>(I, T, meanT, InT, TnT);
    cx_strip<<<dim3(PP / 32, NN), 512, 0, stream>>>(TnT, InT, loss_acc);
    finalize_kernel<<<1, 1, 0, stream>>>(loss_acc, out);
}

// Round 6
// 114.552 us; speedup vs baseline: 1.1891x; 1.0643x over previous
//
#include <hip/hip_runtime.h>
#include <math.h>

#define PP 4096   // P = H*W
#define CC 256    // channels
#define NN 2      // batch
#define NSTEP 16  // 4096 q-rows / 256 per step

typedef __attribute__((ext_vector_type(4))) float f32x4;

__device__ __forceinline__ void gld_lds16(const char* g, char* l) {
    __builtin_amdgcn_global_load_lds(
        (const __attribute__((address_space(1))) unsigned int*)g,
        (__attribute__((address_space(3))) unsigned int*)l, 16, 0, 0);
}

// [journal r15: round-5 strip measured 53us (MfmaUtil 24%, occ 19%): the
//  per-step __syncthreads drains vmcnt(0) INCLUDING the just-issued prefetch
//  -> no cross-step overlap, 1 block/CU -> nothing hides the stall. Fix:
//  A-rows are PRIVATE to each wave (wave wv reads only rows wv*32..+31), so
//  stage into per-wave LDS regions and drop ALL main-loop barriers; per-wave
//  counted s_waitcnt vmcnt(8). s_waitcnt cannot hang (monotone retire) --
//  r14's hang surface was divergent s_barrier, not waitcnt. Loop body has no
//  other VMEM ops; sched_barrier(0) after the wait fences ds_read hoisting.]
// [journal r13: per-block agent-scope ACQ_REL fences in many-block kernels
//  cost +40us (fence storm). Strip kernel: block-local stats, ONE atomicAdd.]
// [journal r11/r12: hipLaunchCooperativeKernel NOT graph-capture-safe here;
//  grid.sync does NOT flush cross-XCD L2. Do not retry cooperative fusion.]
// [journal r10: MX-scaled MFMA regressed -- not MFMA-bound. Keep 16x16x32 fp8.]

// ---- kernel 1: meanT[c] = mean over (n,p) of T (float4 loads); init loss ----
__global__ __launch_bounds__(256) void mean_kernel(const float* __restrict__ T,
                                                   float* __restrict__ meanT,
                                                   float* __restrict__ loss_acc) {
    int c = blockIdx.x, tid = threadIdx.x;
    float s = 0.f;
    for (int n = 0; n < NN; n++) {
        const float4* Tc = (const float4*)&T[(size_t)(n * CC + c) * PP];
        for (int g = 0; g < 4; g++) {
            float4 v = Tc[tid + g * 256];
            s += (v.x + v.y) + (v.z + v.w);
        }
    }
    __shared__ float red[256];
    red[tid] = s; __syncthreads();
    for (int st = 128; st > 0; st >>= 1) {
        if (tid < st) red[tid] += red[tid + st];
        __syncthreads();
    }
    if (tid == 0) meanT[c] = red[0] * (1.0f / (NN * PP));
    if (blockIdx.x == 0 && tid < NN) loss_acc[tid] = 0.f;
}

// ---- kernel 2: center by meanT, L2-normalize over C, write FP8 e4m3 [n][p][c] ----
__global__ __launch_bounds__(256) void normalize_kernel(const float* __restrict__ I,
                                                        const float* __restrict__ T,
                                                        const float* __restrict__ meanT,
                                                        char* __restrict__ InT,
                                                        char* __restrict__ TnT) {
    int pc = blockIdx.x * 32;      // 32 positions per block
    int n = blockIdx.y;
    int which = blockIdx.z;        // 0: I -> InT, 1: T -> TnT
    const float* X = which ? T : I;
    char* Y = which ? TnT : InT;

    __shared__ float tile[CC][36];   // [c][p_local], pad 36 (16B-aligned rows)
    __shared__ float red[32][32];    // [c-group][p_local]
    __shared__ float invn[32];

    int tid = threadIdx.x;
    int pl4 = tid & 7, c0 = tid >> 3;   // 32 c-groups x 8 p-quads
    float sq0 = 0.f, sq1 = 0.f, sq2 = 0.f, sq3 = 0.f;
    for (int c = c0; c < CC; c += 32) {
        float m = meanT[c];
        float4 v = *(const float4*)&X[(size_t)(n * CC + c) * PP + pc + pl4 * 4];
        v.x -= m; v.y -= m; v.z -= m; v.w -= m;
        *(float4*)&tile[c][pl4 * 4] = v;
        sq0 += v.x * v.x; sq1 += v.y * v.y; sq2 += v.z * v.z; sq3 += v.w * v.w;
    }
    red[c0][pl4 * 4 + 0] = sq0;
    red[c0][pl4 * 4 + 1] = sq1;
    red[c0][pl4 * 4 + 2] = sq2;
    red[c0][pl4 * 4 + 3] = sq3;
    __syncthreads();
    if (tid < 32) {
        float s = 0.f;
        for (int k = 0; k < 32; k++) s += red[k][tid];
        invn[tid] = 1.0f / sqrtf(s);
    }
    __syncthreads();
    for (int pass = 0; pass < 8; pass++) {
        int r = pass * 4 + (tid >> 6);
        int c4 = (tid & 63) * 4;
        float in = invn[r];
        float v0 = tile[c4 + 0][r] * in;
        float v1 = tile[c4 + 1][r] * in;
        float v2 = tile[c4 + 2][r] * in;
        float v3 = tile[c4 + 3][r] * in;
        int w = __builtin_amdgcn_cvt_pk_fp8_f32(v0, v1, 0, false);
        w = __builtin_amdgcn_cvt_pk_fp8_f32(v2, v3, w, true);
        *(unsigned*)&Y[(size_t)(n * PP + pc + r) * CC + c4] = (unsigned)w;
    }
}

// ---- kernel 3: strip kernel -- each block owns 32 p-columns x all 4096 q ----
// Pass 0: col-min of raw=(1-dot)/2 block-locally. Pass 1: recompute dots,
// w=exp2(14.427-raw*inv2), col-sums S + diag w, ONE atomicAdd per block.
// A-rows are wave-private (wave wv computes rows wv*32+[0,32) of each step):
// per-wave double-buffered LDS regions Aw[wv][2], staged via gld_lds16, with
// NO barriers in the main loop -- per-wave s_waitcnt vmcnt(8) keeps the next
// step's 8 loads in flight while guaranteeing the current buffer landed
// (FIFO retire). B (8 KB, shared by all waves) staged once + one prologue
// __syncthreads, then held in 32 VGPR of b-frags.
// Chunk-XOR swizzle (validated r5): LDS 16B chunk s of row r holds global
// chunk s^(r&15); read addr for 8B granule g8 = r*256 + ((g8>>1)^(r&15))*16
// + (g8&1)*8.
__global__ __launch_bounds__(512) void cx_strip(const char* __restrict__ TnT,
                                                const char* __restrict__ InT,
                                                float* __restrict__ loss_acc) {
    const int strip = blockIdx.x;       // 0..127
    const int n = blockIdx.y;
    const int p0 = strip * 32;
    const char* __restrict__ Ab = TnT + (size_t)n * PP * CC;            // q rows
    const char* __restrict__ Bb = InT + (size_t)n * PP * CC + (size_t)p0 * CC;

    __shared__ __align__(16) char Aw[8][2][8192];   // per-wave dbuf, 128 KB
    __shared__ __align__(16) char Bsm[8192];        // 8 KB
    __shared__ float redw[8][32];
    __shared__ float inv2s[32];
    __shared__ float dwl[32];

    const int tid = threadIdx.x;
    const int l = tid & 63, wv = tid >> 6;
    const int lm = l & 15, quad = l >> 4;
    const int lr4 = l >> 4;      // lane's row-within-1KB-issue (0..3)
    const int sl = l & 15;       // lane's 16B slot (0..15)

    // stage A step `qs` into per-wave buffer b: 8 issues x 1 KB; lane l of
    // issue g covers (local row g*4+lr4, slot sl), src chunk = sl^(row&15).
#define STAGE_A(qs, b)                                                       \
    {                                                                        \
        const char* sbase_ = Ab + ((size_t)(qs) * 256 + wv * 32) * 256;      \
        char* dbase_ = &Aw[wv][b][0];                                        \
        _Pragma("unroll")                                                    \
        for (int g_ = 0; g_ < 8; g_++) {                                     \
            int row_ = g_ * 4 + lr4;                                         \
            gld_lds16(sbase_ + row_ * 256 + ((sl ^ (row_ & 15)) * 16),       \
                      dbase_ + g_ * 1024);                                   \
        }                                                                    \
    }

    // ---- prologue: stage B (1 issue/wave) + A step 0 into buf0 ----
    {
        int rB = wv * 4 + lr4;   // wave wv covers B rows wv*4..wv*4+3
        gld_lds16(Bb + rB * 256 + ((sl ^ (rB & 15)) * 16), &Bsm[wv * 1024]);
    }
    STAGE_A(0, 0);
    __syncthreads();   // drains vmcnt(0) everywhere: B + all buf0 visible

    // hoist b-frags: bf[ct][ks], 8B each (32 VGPR total)
    long bf[2][8];
#pragma unroll
    for (int ct = 0; ct < 2; ct++)
#pragma unroll
        for (int ks = 0; ks < 8; ks++) {
            int g8 = ks * 4 + quad;
            int row = ct * 16 + lm;
            bf[ct][ks] = *(const long*)&Bsm[row * 256 +
                          (((g8 >> 1) ^ (row & 15)) * 16) + (g8 & 1) * 8];
        }

    float cm[2] = {3.4e38f, 3.4e38f};
    float inv2[2] = {0.f, 0.f};
    float ss[2] = {0.f, 0.f};
    const int qd = p0 >> 8;        // diag step (qd*256 + wd*32 == p0)
    const int wd = (p0 >> 5) & 7;  // diag wave

#pragma unroll 1
    for (int pass = 0; pass < 2; pass++) {
        if (pass == 1) STAGE_A(0, 0);  // restage step 0 (this wave finished
                                       // all pass-0 reads; vm was drained)
#pragma unroll 1
        for (int qs = 0; qs < NSTEP; qs++) {
            // issue next step into the other buffer, keep it in flight:
            // vmcnt(8) waits only until the CURRENT buffer's 8 loads retired.
            if (qs < NSTEP - 1) {
                STAGE_A(qs + 1, (qs + 1) & 1);
                asm volatile("s_waitcnt vmcnt(8)" ::: "memory");
            } else {
                asm volatile("s_waitcnt vmcnt(0)" ::: "memory");
            }
            __builtin_amdgcn_sched_barrier(0);  // no ds_read above the wait

            const char* Ac = &Aw[wv][qs & 1][0];
            f32x4 acc[2][2] = {};
#pragma unroll
            for (int ks = 0; ks < 8; ks++) {
                const int off = (((ks * 2 + (quad >> 1)) ^ lm) * 16) + (quad & 1) * 8;
                long a[2];
#pragma unroll
                for (int i = 0; i < 2; i++)
                    a[i] = *(const long*)&Ac[(i * 16 + lm) * 256 + off];
#pragma unroll
                for (int i = 0; i < 2; i++)
#pragma unroll
                    for (int ct = 0; ct < 2; ct++)
                        acc[i][ct] = __builtin_amdgcn_mfma_f32_16x16x32_fp8_fp8(
                            a[i], bf[ct][ks], acc[i][ct], 0, 0, 0);
            }
            if (pass == 0) {
#pragma unroll
                for (int ct = 0; ct < 2; ct++)
#pragma unroll
                    for (int i = 0; i < 2; i++)
#pragma unroll
                        for (int e = 0; e < 4; e++)
                            cm[ct] = fminf(cm[ct], (1.0f - acc[i][ct][e]) * 0.5f);
            } else {
                const bool dstep = (qs == qd) && (wv == wd);
#pragma unroll
                for (int ct = 0; ct < 2; ct++) {
                    float s2 = 0.f;
#pragma unroll
                    for (int i = 0; i < 2; i++)
#pragma unroll
                        for (int e = 0; e < 4; e++) {
                            float raw = (1.0f - acc[i][ct][e]) * 0.5f;
                            float w = exp2f(fmaf(raw, -inv2[ct], 14.4269504f));
                            s2 += w;
                            // diag: q = p0+i*16+quad*4+e matches p = p0+ct*16+lm
                            if (dstep && (i * 16 + quad * 4 + e == ct * 16 + lm))
                                dwl[ct * 16 + lm] = w;
                        }
                    ss[ct] += s2;
                }
            }
        }

        if (pass == 0) {  // reduce col-mins -> inv2 per col (waves converged,
                          // all vm drained by the last vmcnt(0))
#pragma unroll
            for (int ct = 0; ct < 2; ct++) {
                cm[ct] = fminf(cm[ct], __shfl_xor(cm[ct], 16));
                cm[ct] = fminf(cm[ct], __shfl_xor(cm[ct], 32));
                if (quad == 0) redw[wv][ct * 16 + lm] = cm[ct];
            }
            __syncthreads();
            if (tid < 32) {
                float m = redw[0][tid];
#pragma unroll
                for (int w2 = 1; w2 < 8; w2++) m = fminf(m, redw[w2][tid]);
                inv2s[tid] = 14.4269504f / (m + 1e-5f);
            }
            __syncthreads();
            inv2[0] = inv2s[lm];
            inv2[1] = inv2s[16 + lm];
        }
    }

    // final: S per col, then partial loss = sum_c dwl[c]/S[c], one atomicAdd
#pragma unroll
    for (int ct = 0; ct < 2; ct++) {
        ss[ct] += __shfl_xor(ss[ct], 16);
        ss[ct] += __shfl_xor(ss[ct], 32);
        if (quad == 0) redw[wv][ct * 16 + lm] = ss[ct];
    }
    __syncthreads();
    if (tid < 32) {
        float s = 0.f;
#pragma unroll
        for (int w2 = 0; w2 < 8; w2++) s += redw[w2][tid];
        float part = dwl[tid] / s;
        part += __shfl_xor(part, 1);
        part += __shfl_xor(part, 2);
        part += __shfl_xor(part, 4);
        part += __shfl_xor(part, 8);
        part += __shfl_xor(part, 16);
        if (tid == 0) atomicAdd(&loss_acc[n], part);
    }
#undef STAGE_A
}

// ---- kernel 4: loss = mean_n -log(0.5 + 0.5 * acc_n/P) ----
__global__ void finalize_kernel(const float* __restrict__ loss_acc,
                                float* __restrict__ out) {
    float m0 = 0.5f + 0.5f * (loss_acc[0] / (float)PP);
    float m1 = 0.5f + 0.5f * (loss_acc[1] / (float)PP);
    out[0] = 0.5f * (-logf(m0) - logf(m1));
}

extern "C" void kernel_launch(void* const* d_in, const int* in_sizes, int n_in,
                              void* d_out, int out_size, void* d_ws, size_t ws_size,
                              hipStream_t stream) {
    const float* I = (const float*)d_in[0];
    const float* T = (const float*)d_in[1];
    float* out = (float*)d_out;

    char* ws = (char*)d_ws;
    const size_t SZ_F8 = (size_t)NN * PP * CC;  // 2 MB each (fp8)
    char* InT = ws;
    char* TnT = ws + SZ_F8;
    float* meanT = (float*)(ws + 2 * SZ_F8);               // 1 KB
    float* loss_acc = (float*)(ws + 2 * SZ_F8 + 32768);    // 8 B

    mean_kernel<<<CC, 256, 0, stream>>>(T, meanT, loss_acc);
    normalize_kernel<<<dim3(PP / 32, NN, 2), 256, 0, stream>>>(I, T, meanT, InT, TnT);
    cx_strip<<<dim3(PP / 32, NN), 512, 0, stream>>>(TnT, InT, loss_acc);
    finalize_kernel<<<1, 1, 0, stream>>>(loss_acc, out);
}

// Round 7
// 108.174 us; speedup vs baseline: 1.2593x; 1.0590x over previous
//
#include <hip/hip_runtime.h>
#include <math.h>

#define PP 4096   // P = H*W
#define CC 256    // channels
#define NN 2      // batch
#define NSTEP 16  // 4096 q-rows / 256 per step

typedef __attribute__((ext_vector_type(4))) float f32x4;
typedef __attribute__((ext_vector_type(8))) int i32x8;

__device__ __forceinline__ void gld_lds16(const char* g, char* l) {
    __builtin_amdgcn_global_load_lds(
        (const __attribute__((address_space(1))) unsigned int*)g,
        (__attribute__((address_space(3))) unsigned int*)l, 16, 0, 0);
}

// [journal r16: r6 counters re-modeled: MFMA cycle cost is per-SIMD (~19.4 cy
//  for 16x16x32 fp8), NOT the per-CU 4.85 -- at 2 waves/SIMD the strip kernel
//  is MFMA+VALU-pipe-bound (MfmaUtil 27% = 13us busy, VALUBusy 39%). This
//  flips r10: MX-scaled MFMA (K=128) halves MFMA busy and occupancy can't
//  drop (LDS-bound 1 block/CU). MX numerics validated r1 (absmax 0.0).
//  VALU diet: max-fold pass0, fma+exp2-fold pass1, diag out of element loop,
//  precomputed staging/LDS addresses.]
// [journal r15: per-step __syncthreads drains the just-issued prefetch ->
//  no overlap. A-rows are wave-private: per-wave LDS dbuf, no main-loop
//  barriers, per-wave s_waitcnt vmcnt(8). waitcnt cannot hang (monotone).]
// [journal r13: per-block agent-scope ACQ_REL fences in many-block kernels
//  cost +40us (fence storm). Strip kernel: block-local stats, ONE atomicAdd.]
// [journal r11/r12: hipLaunchCooperativeKernel NOT graph-capture-safe here;
//  grid.sync does NOT flush cross-XCD L2. Do not retry cooperative fusion.]

// ---- kernel 1: meanT[c] = mean over (n,p) of T (float4 loads); init loss ----
__global__ __launch_bounds__(256) void mean_kernel(const float* __restrict__ T,
                                                   float* __restrict__ meanT,
                                                   float* __restrict__ loss_acc) {
    int c = blockIdx.x, tid = threadIdx.x;
    float s = 0.f;
    for (int n = 0; n < NN; n++) {
        const float4* Tc = (const float4*)&T[(size_t)(n * CC + c) * PP];
        for (int g = 0; g < 4; g++) {
            float4 v = Tc[tid + g * 256];
            s += (v.x + v.y) + (v.z + v.w);
        }
    }
    __shared__ float red[256];
    red[tid] = s; __syncthreads();
    for (int st = 128; st > 0; st >>= 1) {
        if (tid < st) red[tid] += red[tid + st];
        __syncthreads();
    }
    if (tid == 0) meanT[c] = red[0] * (1.0f / (NN * PP));
    if (blockIdx.x == 0 && tid < NN) loss_acc[tid] = 0.f;
}

// ---- kernel 2: center by meanT, L2-normalize over C, write FP8 e4m3 [n][p][c] ----
__global__ __launch_bounds__(256) void normalize_kernel(const float* __restrict__ I,
                                                        const float* __restrict__ T,
                                                        const float* __restrict__ meanT,
                                                        char* __restrict__ InT,
                                                        char* __restrict__ TnT) {
    int pc = blockIdx.x * 32;      // 32 positions per block
    int n = blockIdx.y;
    int which = blockIdx.z;        // 0: I -> InT, 1: T -> TnT
    const float* X = which ? T : I;
    char* Y = which ? TnT : InT;

    __shared__ float tile[CC][36];   // [c][p_local], pad 36 (16B-aligned rows)
    __shared__ float red[32][32];    // [c-group][p_local]
    __shared__ float invn[32];

    int tid = threadIdx.x;
    int pl4 = tid & 7, c0 = tid >> 3;   // 32 c-groups x 8 p-quads
    float sq0 = 0.f, sq1 = 0.f, sq2 = 0.f, sq3 = 0.f;
    for (int c = c0; c < CC; c += 32) {
        float m = meanT[c];
        float4 v = *(const float4*)&X[(size_t)(n * CC + c) * PP + pc + pl4 * 4];
        v.x -= m; v.y -= m; v.z -= m; v.w -= m;
        *(float4*)&tile[c][pl4 * 4] = v;
        sq0 += v.x * v.x; sq1 += v.y * v.y; sq2 += v.z * v.z; sq3 += v.w * v.w;
    }
    red[c0][pl4 * 4 + 0] = sq0;
    red[c0][pl4 * 4 + 1] = sq1;
    red[c0][pl4 * 4 + 2] = sq2;
    red[c0][pl4 * 4 + 3] = sq3;
    __syncthreads();
    if (tid < 32) {
        float s = 0.f;
        for (int k = 0; k < 32; k++) s += red[k][tid];
        invn[tid] = 1.0f / sqrtf(s);
    }
    __syncthreads();
    for (int pass = 0; pass < 8; pass++) {
        int r = pass * 4 + (tid >> 6);
        int c4 = (tid & 63) * 4;
        float in = invn[r];
        float v0 = tile[c4 + 0][r] * in;
        float v1 = tile[c4 + 1][r] * in;
        float v2 = tile[c4 + 2][r] * in;
        float v3 = tile[c4 + 3][r] * in;
        int w = __builtin_amdgcn_cvt_pk_fp8_f32(v0, v1, 0, false);
        w = __builtin_amdgcn_cvt_pk_fp8_f32(v2, v3, w, true);
        *(unsigned*)&Y[(size_t)(n * PP + pc + r) * CC + c4] = (unsigned)w;
    }
}

// ---- kernel 3: strip kernel -- each block owns 32 p-columns x all 4096 q ----
// Pass 0: col-max of dot (== col-min of raw=(1-dot)/2) block-locally.
// Pass 1: recompute dots, w = exp2(fma(dot, inv2/2, 14.427-inv2/2))
//         [exact algebra of exp2(14.427 - raw*inv2)], col-sums + diag,
//         ONE atomicAdd(loss_acc[n]) per block.
// MFMA: MX-scaled mfma_scale_f32_16x16x128_f8f6f4, unit scales (E8M0=127).
// Same staged bytes/swizzle as the validated 16x16x32 version; the 8-dword
// operand concatenates 4 k-slices (granule kb*16 + j*4 + quad, j ascending)
// -- layout validated end-to-end in r1 (absmax 0.0).
// Staging: per-wave double-buffered LDS (A-rows are wave-private), no
// main-loop barriers, per-wave s_waitcnt vmcnt(8) (next step in flight).
// Chunk-XOR swizzle: LDS 16B chunk s of row r holds global chunk s^(r&15).
__global__ __launch_bounds__(512) void cx_strip(const char* __restrict__ TnT,
                                                const char* __restrict__ InT,
                                                float* __restrict__ loss_acc) {
    const int strip = blockIdx.x;       // 0..127
    const int n = blockIdx.y;
    const int p0 = strip * 32;
    const char* __restrict__ Ab = TnT + (size_t)n * PP * CC;            // q rows
    const char* __restrict__ Bb = InT + (size_t)n * PP * CC + (size_t)p0 * CC;

    __shared__ __align__(16) char Aw[8][2][8192];   // per-wave dbuf, 128 KB
    __shared__ __align__(16) char Bsm[8192];        // 8 KB
    __shared__ float redw[8][32];
    __shared__ float inv2s[32];
    __shared__ float dwl[32];

    const int tid = threadIdx.x;
    const int l = tid & 63, wv = tid >> 6;
    const int lm = l & 15, quad = l >> 4;
    const int lr4 = l >> 4;      // lane's row-within-1KB-issue (0..3)
    const int sl = l & 15;       // lane's 16B slot (0..15)

    // precompute per-lane global srcs for step 0 (advance by qs*65536)
    const char* asrc[8];
#pragma unroll
    for (int g = 0; g < 8; g++) {
        int row = g * 4 + lr4;
        asrc[g] = Ab + (size_t)(wv * 32 + row) * 256 + ((sl ^ (row & 15)) * 16);
    }
#define STAGE_A(qs, b)                                                        \
    {                                                                         \
        char* dbase_ = &Aw[wv][b][0];                                         \
        _Pragma("unroll")                                                     \
        for (int g_ = 0; g_ < 8; g_++)                                        \
            gld_lds16(asrc[g_] + (size_t)(qs) * 65536, dbase_ + g_ * 1024);   \
    }

    // precompute LDS read offsets within a wave buffer: aoff[i*8 + kb*4 + j]
    // granule g8 = kb*16 + j*4 + quad; byte = ((g8>>1)^lm)*16 + (g8&1)*8
    int aoff[16];
#pragma unroll
    for (int i = 0; i < 2; i++)
#pragma unroll
        for (int kb = 0; kb < 2; kb++)
#pragma unroll
            for (int j = 0; j < 4; j++)
                aoff[i * 8 + kb * 4 + j] =
                    (i * 16 + lm) * 256 +
                    (((kb * 8 + j * 2 + (quad >> 1)) ^ lm) * 16) + (quad & 1) * 8;

    // ---- prologue: stage B (1 issue/wave) + A step 0 into buf0 ----
    {
        int rB = wv * 4 + lr4;   // wave wv covers B rows wv*4..wv*4+3
        gld_lds16(Bb + rB * 256 + ((sl ^ (rB & 15)) * 16), &Bsm[wv * 1024]);
    }
    STAGE_A(0, 0);
    __syncthreads();   // drains vmcnt(0) everywhere: B + all buf0 visible

    // hoist b-frags; view as i32x8 per (ct, kb) for the MX operand
    union BU { long l[2][8]; i32x8 v[2][2]; } bfu;
#pragma unroll
    for (int ct = 0; ct < 2; ct++)
#pragma unroll
        for (int ks = 0; ks < 8; ks++) {
            int g8 = ks * 4 + quad;
            int row = ct * 16 + lm;
            bfu.l[ct][ks] = *(const long*)&Bsm[row * 256 +
                             (((g8 >> 1) ^ (row & 15)) * 16) + (g8 & 1) * 8];
        }

    float amax[2] = {-3.4e38f, -3.4e38f};
    float hc[2] = {0.f, 0.f}, c0c[2] = {0.f, 0.f};
    float ss[2] = {0.f, 0.f};
    const int qd = p0 >> 8;        // diag step (qd*256 + wd*32 == p0)
    const int wd = (p0 >> 5) & 7;  // diag wave

#pragma unroll 1
    for (int pass = 0; pass < 2; pass++) {
        if (pass == 1) STAGE_A(0, 0);  // restage step 0 (vm fully drained)
#pragma unroll 1
        for (int qs = 0; qs < NSTEP; qs++) {
            if (qs < NSTEP - 1) {
                STAGE_A(qs + 1, (qs + 1) & 1);
                asm volatile("s_waitcnt vmcnt(8)" ::: "memory");
            } else {
                asm volatile("s_waitcnt vmcnt(0)" ::: "memory");
            }
            __builtin_amdgcn_sched_barrier(0);  // no ds_read above the wait

            const char* Ac = &Aw[wv][qs & 1][0];
            f32x4 acc[2][2] = {};
#pragma unroll
            for (int kb = 0; kb < 2; kb++) {
                union AU { long l[4]; i32x8 v; } a_[2];
#pragma unroll
                for (int j = 0; j < 4; j++)
#pragma unroll
                    for (int i = 0; i < 2; i++)
                        a_[i].l[j] = *(const long*)&Ac[aoff[i * 8 + kb * 4 + j]];
#pragma unroll
                for (int i = 0; i < 2; i++)
#pragma unroll
                    for (int ct = 0; ct < 2; ct++)
                        acc[i][ct] = __builtin_amdgcn_mfma_scale_f32_16x16x128_f8f6f4(
                            a_[i].v, bfu.v[ct][kb], acc[i][ct],
                            0, 0,                // cbsz=0 (e4m3), blgp=0 (e4m3)
                            0, 0x7f7f7f7f,       // scale_a sel, 1.0
                            0, 0x7f7f7f7f);      // scale_b sel, 1.0
            }
            if (pass == 0) {
#pragma unroll
                for (int ct = 0; ct < 2; ct++)
#pragma unroll
                    for (int i = 0; i < 2; i++)
#pragma unroll
                        for (int e = 0; e < 4; e++)
                            amax[ct] = fmaxf(amax[ct], acc[i][ct][e]);
            } else {
#pragma unroll
                for (int ct = 0; ct < 2; ct++) {
                    float s2 = 0.f;
#pragma unroll
                    for (int i = 0; i < 2; i++)
#pragma unroll
                        for (int e = 0; e < 4; e++)
                            s2 += exp2f(fmaf(acc[i][ct][e], hc[ct], c0c[ct]));
                    ss[ct] += s2;
                }
                if ((qs == qd) && (wv == wd)) {   // wave-uniform branch
#pragma unroll
                    for (int ct = 0; ct < 2; ct++)
                        if (quad == (lm >> 2))    // unique lane per column
                            dwl[ct * 16 + lm] = exp2f(
                                fmaf(acc[ct][ct][lm & 3], hc[ct], c0c[ct]));
                }
            }
        }

        if (pass == 0) {  // reduce col-maxes -> inv2 coefs per col
#pragma unroll
            for (int ct = 0; ct < 2; ct++) {
                amax[ct] = fmaxf(amax[ct], __shfl_xor(amax[ct], 16));
                amax[ct] = fmaxf(amax[ct], __shfl_xor(amax[ct], 32));
                if (quad == 0) redw[wv][ct * 16 + lm] = amax[ct];
            }
            __syncthreads();
            if (tid < 32) {
                float mx = redw[0][tid];
#pragma unroll
                for (int w2 = 1; w2 < 8; w2++) mx = fmaxf(mx, redw[w2][tid]);
                float mnv = (1.0f - mx) * 0.5f;            // column min of raw
                inv2s[tid] = 14.4269504f / (mnv + 1e-5f);
            }
            __syncthreads();
            {
                float i20 = inv2s[lm], i21 = inv2s[16 + lm];
                hc[0] = i20 * 0.5f; c0c[0] = 14.4269504f - hc[0];
                hc[1] = i21 * 0.5f; c0c[1] = 14.4269504f - hc[1];
            }
        }
    }

    // final: S per col, then partial loss = sum_c dwl[c]/S[c], one atomicAdd
#pragma unroll
    for (int ct = 0; ct < 2; ct++) {
        ss[ct] += __shfl_xor(ss[ct], 16);
        ss[ct] += __shfl_xor(ss[ct], 32);
        if (quad == 0) redw[wv][ct * 16 + lm] = ss[ct];
    }
    __syncthreads();
    if (tid < 32) {
        float s = 0.f;
#pragma unroll
        for (int w2 = 0; w2 < 8; w2++) s += redw[w2][tid];
        float part = dwl[tid] / s;
        part += __shfl_xor(part, 1);
        part += __shfl_xor(part, 2);
        part += __shfl_xor(part, 4);
        part += __shfl_xor(part, 8);
        part += __shfl_xor(part, 16);
        if (tid == 0) atomicAdd(&loss_acc[n], part);
    }
#undef STAGE_A
}

// ---- kernel 4: loss = mean_n -log(0.5 + 0.5 * acc_n/P) ----
__global__ void finalize_kernel(const float* __restrict__ loss_acc,
                                float* __restrict__ out) {
    float m0 = 0.5f + 0.5f * (loss_acc[0] / (float)PP);
    float m1 = 0.5f + 0.5f * (loss_acc[1] / (float)PP);
    out[0] = 0.5f * (-logf(m0) - logf(m1));
}

extern "C" void kernel_launch(void* const* d_in, const int* in_sizes, int n_in,
                              void* d_out, int out_size, void* d_ws, size_t ws_size,
                              hipStream_t stream) {
    const float* I = (const float*)d_in[0];
    const float* T = (const float*)d_in[1];
    float* out = (float*)d_out;

    char* ws = (char*)d_ws;
    const size_t SZ_F8 = (size_t)NN * PP * CC;  // 2 MB each (fp8)
    char* InT = ws;
    char* TnT = ws + SZ_F8;
    float* meanT = (float*)(ws + 2 * SZ_F8);               // 1 KB
    float* loss_acc = (float*)(ws + 2 * SZ_F8 + 32768);    // 8 B

    mean_kernel<<<CC, 256, 0, stream>>>(T, meanT, loss_acc);
    normalize_kernel<<<dim3(PP / 32, NN, 2), 256, 0, stream>>>(I, T, meanT, InT, TnT);
    cx_strip<<<dim3(PP / 32, NN), 512, 0, stream>>>(TnT, InT, loss_acc);
    finalize_kernel<<<1, 1, 0, stream>>>(loss_acc, out);
}

// Round 8
// 105.368 us; speedup vs baseline: 1.2928x; 1.0266x over previous
//
#include <hip/hip_runtime.h>
#include <math.h>

#define PP 4096   // P = H*W
#define CC 256    // channels
#define NN 2      // batch
#define NSTEP 16  // 4096 q-rows / 256 per step

typedef __attribute__((ext_vector_type(4))) float f32x4;
typedef __attribute__((ext_vector_type(8))) int i32x8;

__device__ __forceinline__ void gld_lds16(const char* g, char* l) {
    __builtin_amdgcn_global_load_lds(
        (const __attribute__((address_space(1))) unsigned int*)g,
        (__attribute__((address_space(3))) unsigned int*)l, 16, 0, 0);
}

// [journal r17: r7 landed 108us (MX + VALU diet, absmax 0.0); strip ~38us vs
//  ~15us L2 floor. Residual = vmcnt wait exposure at 2 waves/SIMD. Fix: 16
//  waves x 16 rows (1024 thr) -> 4 waves/SIMD, per-wave staging/MFMA/VALU
//  halved, same aggregate. ~44us of dur is the harness ws-poison fill (in
//  the timed window, unavoidable).]
// [journal r16: MFMA cycle cost is per-SIMD (~34.6 cy for MX 16x16x128, ~19.4
//  for 16x16x32 fp8), NOT the per-CU numbers. MX halves MFMA busy; validated.]
// [journal r15: A-rows are wave-private: per-wave LDS dbuf, no main-loop
//  barriers, per-wave counted s_waitcnt. waitcnt cannot hang (monotone).]
// [journal r13: per-block agent-scope ACQ_REL fences in many-block kernels
//  cost +40us (fence storm). Strip kernel: block-local stats, ONE atomicAdd.]
// [journal r11/r12: hipLaunchCooperativeKernel NOT graph-capture-safe here;
//  grid.sync does NOT flush cross-XCD L2. Do not retry cooperative fusion.]

// ---- kernel 1: meanT[c] = mean over (n,p) of T (float4 loads); init loss ----
__global__ __launch_bounds__(256) void mean_kernel(const float* __restrict__ T,
                                                   float* __restrict__ meanT,
                                                   float* __restrict__ loss_acc) {
    int c = blockIdx.x, tid = threadIdx.x;
    float s = 0.f;
    for (int n = 0; n < NN; n++) {
        const float4* Tc = (const float4*)&T[(size_t)(n * CC + c) * PP];
        for (int g = 0; g < 4; g++) {
            float4 v = Tc[tid + g * 256];
            s += (v.x + v.y) + (v.z + v.w);
        }
    }
    __shared__ float red[256];
    red[tid] = s; __syncthreads();
    for (int st = 128; st > 0; st >>= 1) {
        if (tid < st) red[tid] += red[tid + st];
        __syncthreads();
    }
    if (tid == 0) meanT[c] = red[0] * (1.0f / (NN * PP));
    if (blockIdx.x == 0 && tid < NN) loss_acc[tid] = 0.f;
}

// ---- kernel 2: center by meanT, L2-normalize over C, write FP8 e4m3 [n][p][c] ----
__global__ __launch_bounds__(256) void normalize_kernel(const float* __restrict__ I,
                                                        const float* __restrict__ T,
                                                        const float* __restrict__ meanT,
                                                        char* __restrict__ InT,
                                                        char* __restrict__ TnT) {
    int pc = blockIdx.x * 32;      // 32 positions per block
    int n = blockIdx.y;
    int which = blockIdx.z;        // 0: I -> InT, 1: T -> TnT
    const float* X = which ? T : I;
    char* Y = which ? TnT : InT;

    __shared__ float tile[CC][36];   // [c][p_local], pad 36 (16B-aligned rows)
    __shared__ float red[32][32];    // [c-group][p_local]
    __shared__ float invn[32];

    int tid = threadIdx.x;
    int pl4 = tid & 7, c0 = tid >> 3;   // 32 c-groups x 8 p-quads
    float sq0 = 0.f, sq1 = 0.f, sq2 = 0.f, sq3 = 0.f;
    for (int c = c0; c < CC; c += 32) {
        float m = meanT[c];
        float4 v = *(const float4*)&X[(size_t)(n * CC + c) * PP + pc + pl4 * 4];
        v.x -= m; v.y -= m; v.z -= m; v.w -= m;
        *(float4*)&tile[c][pl4 * 4] = v;
        sq0 += v.x * v.x; sq1 += v.y * v.y; sq2 += v.z * v.z; sq3 += v.w * v.w;
    }
    red[c0][pl4 * 4 + 0] = sq0;
    red[c0][pl4 * 4 + 1] = sq1;
    red[c0][pl4 * 4 + 2] = sq2;
    red[c0][pl4 * 4 + 3] = sq3;
    __syncthreads();
    if (tid < 32) {
        float s = 0.f;
        for (int k = 0; k < 32; k++) s += red[k][tid];
        invn[tid] = 1.0f / sqrtf(s);
    }
    __syncthreads();
    for (int pass = 0; pass < 8; pass++) {
        int r = pass * 4 + (tid >> 6);
        int c4 = (tid & 63) * 4;
        float in = invn[r];
        float v0 = tile[c4 + 0][r] * in;
        float v1 = tile[c4 + 1][r] * in;
        float v2 = tile[c4 + 2][r] * in;
        float v3 = tile[c4 + 3][r] * in;
        int w = __builtin_amdgcn_cvt_pk_fp8_f32(v0, v1, 0, false);
        w = __builtin_amdgcn_cvt_pk_fp8_f32(v2, v3, w, true);
        *(unsigned*)&Y[(size_t)(n * PP + pc + r) * CC + c4] = (unsigned)w;
    }
}

// ---- kernel 3: strip kernel -- block owns 32 p-cols x all 4096 q; 16 waves
// x 16 A-rows each (4 waves/SIMD for latency hiding). Pass 0: col-max of dot
// (== col-min of raw) block-locally. Pass 1: recompute dots, w = exp2(fma(
// dot, inv2/2, 14.427-inv2/2)), col-sums + diag, ONE atomicAdd per block.
// MFMA: MX-scaled mfma_scale_f32_16x16x128_f8f6f4, unit scales (validated
// r1/r7, absmax 0.0). Per-wave double-buffered LDS (A-rows wave-private), no
// main-loop barriers, per-wave s_waitcnt vmcnt(4) (next step in flight).
// Chunk-XOR swizzle: LDS 16B chunk s of row r holds global chunk s^(r&15).
__global__ __launch_bounds__(1024) void cx_strip(const char* __restrict__ TnT,
                                                 const char* __restrict__ InT,
                                                 float* __restrict__ loss_acc) {
    const int strip = blockIdx.x;       // 0..127
    const int n = blockIdx.y;
    const int p0 = strip * 32;
    const char* __restrict__ Ab = TnT + (size_t)n * PP * CC;            // q rows
    const char* __restrict__ Bb = InT + (size_t)n * PP * CC + (size_t)p0 * CC;

    __shared__ __align__(16) char Aw[16][2][4096];  // per-wave dbuf, 128 KB
    __shared__ __align__(16) char Bsm[8192];        // 8 KB
    __shared__ float redw[16][32];
    __shared__ float inv2s[32];
    __shared__ float dwl[32];

    const int tid = threadIdx.x;
    const int l = tid & 63, wv = tid >> 6;          // wv 0..15
    const int lm = l & 15, quad = l >> 4;
    const int lr4 = l >> 4;      // lane's row-within-1KB-issue (0..3)
    const int sl = l & 15;       // lane's 16B slot (0..15)

    // per-lane global srcs for step 0 (advance by qs*65536); 4 issues x 1 KB
    const char* asrc[4];
#pragma unroll
    for (int g = 0; g < 4; g++) {
        int row = g * 4 + lr4;   // local row 0..15 within this wave's 16
        asrc[g] = Ab + (size_t)(wv * 16 + row) * 256 + ((sl ^ (row & 15)) * 16);
    }
#define STAGE_A(qs, b)                                                        \
    {                                                                         \
        char* dbase_ = &Aw[wv][b][0];                                         \
        _Pragma("unroll")                                                     \
        for (int g_ = 0; g_ < 4; g_++)                                        \
            gld_lds16(asrc[g_] + (size_t)(qs) * 65536, dbase_ + g_ * 1024);   \
    }

    // LDS read offsets: aoff[kb*4 + j]; granule g8 = kb*16 + j*4 + quad;
    // byte = row*256 + ((g8>>1)^row)*16 + (g8&1)*8, row = lm
    int aoff[8];
#pragma unroll
    for (int kb = 0; kb < 2; kb++)
#pragma unroll
        for (int j = 0; j < 4; j++)
            aoff[kb * 4 + j] = lm * 256 +
                (((kb * 8 + j * 2 + (quad >> 1)) ^ lm) * 16) + (quad & 1) * 8;

    // ---- prologue: stage B (waves 0..7, 1 issue each) + A step 0 ----
    if (wv < 8) {
        int rB = wv * 4 + lr4;   // wave wv covers B rows wv*4..wv*4+3
        gld_lds16(Bb + rB * 256 + ((sl ^ (rB & 15)) * 16), &Bsm[wv * 1024]);
    }
    STAGE_A(0, 0);
    __syncthreads();   // drains vmcnt(0) everywhere: B + all buf0 visible

    // hoist b-frags; view as i32x8 per (ct, kb) for the MX operand
    union BU { long l[2][8]; i32x8 v[2][2]; } bfu;
#pragma unroll
    for (int ct = 0; ct < 2; ct++)
#pragma unroll
        for (int ks = 0; ks < 8; ks++) {
            int g8 = ks * 4 + quad;
            int row = ct * 16 + lm;
            bfu.l[ct][ks] = *(const long*)&Bsm[row * 256 +
                             (((g8 >> 1) ^ (row & 15)) * 16) + (g8 & 1) * 8];
        }

    float amax[2] = {-3.4e38f, -3.4e38f};
    float hc[2] = {0.f, 0.f}, c0c[2] = {0.f, 0.f};
    float ss[2] = {0.f, 0.f};
    // diag for col p0+ct*16+lm lives at global q = p0+ct*16+lm:
    // step qdd[ct] = (p0+ct*16)>>8, wave wdd[ct] = ((p0+ct*16)>>4)&15
    const int qdd0 = p0 >> 8, wdd0 = (p0 >> 4) & 15;
    const int qdd1 = (p0 + 16) >> 8, wdd1 = ((p0 + 16) >> 4) & 15;

#pragma unroll 1
    for (int pass = 0; pass < 2; pass++) {
        if (pass == 1) STAGE_A(0, 0);  // restage step 0 (own buf, vm drained)
#pragma unroll 1
        for (int qs = 0; qs < NSTEP; qs++) {
            if (qs < NSTEP - 1) {
                STAGE_A(qs + 1, (qs + 1) & 1);
                asm volatile("s_waitcnt vmcnt(4)" ::: "memory");
            } else {
                asm volatile("s_waitcnt vmcnt(0)" ::: "memory");
            }
            __builtin_amdgcn_sched_barrier(0);  // no ds_read above the wait

            const char* Ac = &Aw[wv][qs & 1][0];
            f32x4 acc[2] = {};
#pragma unroll
            for (int kb = 0; kb < 2; kb++) {
                union AU { long l[4]; i32x8 v; } a_;
#pragma unroll
                for (int j = 0; j < 4; j++)
                    a_.l[j] = *(const long*)&Ac[aoff[kb * 4 + j]];
#pragma unroll
                for (int ct = 0; ct < 2; ct++)
                    acc[ct] = __builtin_amdgcn_mfma_scale_f32_16x16x128_f8f6f4(
                        a_.v, bfu.v[ct][kb], acc[ct],
                        0, 0,                // cbsz=0 (e4m3), blgp=0 (e4m3)
                        0, 0x7f7f7f7f,       // scale_a sel, 1.0
                        0, 0x7f7f7f7f);      // scale_b sel, 1.0
            }
            if (pass == 0) {
#pragma unroll
                for (int ct = 0; ct < 2; ct++)
#pragma unroll
                    for (int e = 0; e < 4; e++)
                        amax[ct] = fmaxf(amax[ct], acc[ct][e]);
            } else {
#pragma unroll
                for (int ct = 0; ct < 2; ct++) {
                    float s2 = 0.f;
#pragma unroll
                    for (int e = 0; e < 4; e++)
                        s2 += exp2f(fmaf(acc[ct][e], hc[ct], c0c[ct]));
                    ss[ct] += s2;
                }
                // diag: local row quad*4+e == lm  <=>  quad==lm>>2, e==lm&3
                if (qs == qdd0 && wv == wdd0 && quad == (lm >> 2))
                    dwl[lm] = exp2f(fmaf(acc[0][lm & 3], hc[0], c0c[0]));
                if (qs == qdd1 && wv == wdd1 && quad == (lm >> 2))
                    dwl[16 + lm] = exp2f(fmaf(acc[1][lm & 3], hc[1], c0c[1]));
            }
        }

        if (pass == 0) {  // reduce col-maxes -> exp2 coefs per col
#pragma unroll
            for (int ct = 0; ct < 2; ct++) {
                amax[ct] = fmaxf(amax[ct], __shfl_xor(amax[ct], 16));
                amax[ct] = fmaxf(amax[ct], __shfl_xor(amax[ct], 32));
                if (quad == 0) redw[wv][ct * 16 + lm] = amax[ct];
            }
            __syncthreads();
            if (tid < 32) {
                float mx = redw[0][tid];
#pragma unroll
                for (int w2 = 1; w2 < 16; w2++) mx = fmaxf(mx, redw[w2][tid]);
                float mnv = (1.0f - mx) * 0.5f;            // column min of raw
                inv2s[tid] = 14.4269504f / (mnv + 1e-5f);
            }
            __syncthreads();
            {
                float i20 = inv2s[lm], i21 = inv2s[16 + lm];
                hc[0] = i20 * 0.5f; c0c[0] = 14.4269504f - hc[0];
                hc[1] = i21 * 0.5f; c0c[1] = 14.4269504f - hc[1];
            }
        }
    }

    // final: S per col, then partial loss = sum_c dwl[c]/S[c], one atomicAdd
#pragma unroll
    for (int ct = 0; ct < 2; ct++) {
        ss[ct] += __shfl_xor(ss[ct], 16);
        ss[ct] += __shfl_xor(ss[ct], 32);
        if (quad == 0) redw[wv][ct * 16 + lm] = ss[ct];
    }
    __syncthreads();
    if (tid < 32) {
        float s = 0.f;
#pragma unroll
        for (int w2 = 0; w2 < 16; w2++) s += redw[w2][tid];
        float part = dwl[tid] / s;
        part += __shfl_xor(part, 1);
        part += __shfl_xor(part, 2);
        part += __shfl_xor(part, 4);
        part += __shfl_xor(part, 8);
        part += __shfl_xor(part, 16);
        if (tid == 0) atomicAdd(&loss_acc[n], part);
    }
#undef STAGE_A
}

// ---- kernel 4: loss = mean_n -log(0.5 + 0.5 * acc_n/P) ----
__global__ void finalize_kernel(const float* __restrict__ loss_acc,
                                float* __restrict__ out) {
    float m0 = 0.5f + 0.5f * (loss_acc[0] / (float)PP);
    float m1 = 0.5f + 0.5f * (loss_acc[1] / (float)PP);
    out[0] = 0.5f * (-logf(m0) - logf(m1));
}

extern "C" void kernel_launch(void* const* d_in, const int* in_sizes, int n_in,
                              void* d_out, int out_size, void* d_ws, size_t ws_size,
                              hipStream_t stream) {
    const float* I = (const float*)d_in[0];
    const float* T = (const float*)d_in[1];
    float* out = (float*)d_out;

    char* ws = (char*)d_ws;
    const size_t SZ_F8 = (size_t)NN * PP * CC;  // 2 MB each (fp8)
    char* InT = ws;
    char* TnT = ws + SZ_F8;
    float* meanT = (float*)(ws + 2 * SZ_F8);               // 1 KB
    float* loss_acc = (float*)(ws + 2 * SZ_F8 + 32768);    // 8 B

    mean_kernel<<<CC, 256, 0, stream>>>(T, meanT, loss_acc);
    normalize_kernel<<<dim3(PP / 32, NN, 2), 256, 0, stream>>>(I, T, meanT, InT, TnT);
    cx_strip<<<dim3(PP / 32, NN), 1024, 0, stream>>>(TnT, InT, loss_acc);
    finalize_kernel<<<1, 1, 0, stream>>>(loss_acc, out);
}